// Round 1
// baseline (92.464 us; speedup 1.0000x reference)
//
#include <hip/hip_runtime.h>

#define ALPHA 0.3f
#define D 2
#define DH 5
#define NH 3

__device__ __forceinline__ float fast_tanh(float z) {
    // tanh(z) = 1 - 2/(exp(2z)+1); exact saturation at +/-inf, ~1e-7 rel err
    float e = __expf(2.0f * z);
    return 1.0f - 2.0f / (e + 1.0f);
}

__device__ __forceinline__ void act_pair(float z, float& h, float& d) {
    float t = fast_tanh(z);
    h = ALPHA * z + (1.0f - ALPHA) * t;
    d = ALPHA + (1.0f - ALPHA) * (1.0f - t * t);
}

__global__ __launch_bounds__(256) void nnflow_kernel(
    const float4* __restrict__ xj4,
    const float* __restrict__ gW0,
    const float* __restrict__ gWs,
    const float* __restrict__ gWout,
    float4* __restrict__ out4,
    int nquads)
{
    int t = blockIdx.x * blockDim.x + threadIdx.x;
    if (t >= nquads) return;

    // ---- load weights (uniform across lanes; tiny, L1-broadcast) ----
    float w0[DH][D];
    #pragma unroll
    for (int k = 0; k < DH; ++k)
        #pragma unroll
        for (int j = 0; j < D; ++j)
            w0[k][j] = gW0[k * D + j];

    float ws[NH][DH][DH];
    #pragma unroll
    for (int i = 0; i < NH; ++i)
        #pragma unroll
        for (int k = 0; k < DH; ++k)
            #pragma unroll
            for (int j = 0; j < DH; ++j)
                ws[i][k][j] = gWs[(i * DH + k) * DH + j];

    float wo[D][DH];
    #pragma unroll
    for (int r = 0; r < D; ++r)
        #pragma unroll
        for (int j = 0; j < DH; ++j)
            wo[r][j] = gWout[r * DH + j];

    // ---- load 4 samples = 12 floats = 3 float4 (perfectly coalesced) ----
    float4 v0 = xj4[(size_t)t * 3 + 0];
    float4 v1 = xj4[(size_t)t * 3 + 1];
    float4 v2 = xj4[(size_t)t * 3 + 2];

    float xs[4][3] = {
        {v0.x, v0.y, v0.z},
        {v0.w, v1.x, v1.y},
        {v1.z, v1.w, v2.x},
        {v2.y, v2.z, v2.w}
    };
    float os[4][3];

    #pragma unroll
    for (int s = 0; s < 4; ++s) {
        float x0 = xs[s][0], x1 = xs[s][1], lj = xs[s][2];

        // layer 0: z = W0 @ x ; J = d[k] * W0
        float h[DH], J0[DH], J1[DH];
        #pragma unroll
        for (int k = 0; k < DH; ++k) {
            float z = w0[k][0] * x0 + w0[k][1] * x1;
            float hk, dk;
            act_pair(z, hk, dk);
            h[k]  = hk;
            J0[k] = dk * w0[k][0];
            J1[k] = dk * w0[k][1];
        }

        // hidden layers
        #pragma unroll
        for (int i = 0; i < NH; ++i) {
            float hn[DH], Jn0[DH], Jn1[DH];
            #pragma unroll
            for (int k = 0; k < DH; ++k) {
                float z = 0.f, j0 = 0.f, j1 = 0.f;
                #pragma unroll
                for (int j = 0; j < DH; ++j) {
                    float w = ws[i][k][j];
                    z  = fmaf(w, h[j],  z);
                    j0 = fmaf(w, J0[j], j0);
                    j1 = fmaf(w, J1[j], j1);
                }
                float hk, dk;
                act_pair(z, hk, dk);
                hn[k]  = hk;
                Jn0[k] = dk * j0;
                Jn1[k] = dk * j1;
            }
            #pragma unroll
            for (int k = 0; k < DH; ++k) { h[k] = hn[k]; J0[k] = Jn0[k]; J1[k] = Jn1[k]; }
        }

        // output layer: 2x2 Jacobian
        float y[2], Jo[2][2];
        #pragma unroll
        for (int r = 0; r < 2; ++r) {
            float z = 0.f, j0 = 0.f, j1 = 0.f;
            #pragma unroll
            for (int j = 0; j < DH; ++j) {
                float w = wo[r][j];
                z  = fmaf(w, h[j],  z);
                j0 = fmaf(w, J0[j], j0);
                j1 = fmaf(w, J1[j], j1);
            }
            float yk, dk;
            act_pair(z, yk, dk);
            y[r] = yk;
            Jo[r][0] = dk * j0;
            Jo[r][1] = dk * j1;
        }

        float det = Jo[0][0] * Jo[1][1] - Jo[0][1] * Jo[1][0];
        float ld = __logf(fabsf(det));

        os[s][0] = y[0];
        os[s][1] = y[1];
        os[s][2] = lj + ld;
    }

    // ---- store 4 samples = 3 float4 ----
    out4[(size_t)t * 3 + 0] = make_float4(os[0][0], os[0][1], os[0][2], os[1][0]);
    out4[(size_t)t * 3 + 1] = make_float4(os[1][1], os[1][2], os[2][0], os[2][1]);
    out4[(size_t)t * 3 + 2] = make_float4(os[2][2], os[3][0], os[3][1], os[3][2]);
}

extern "C" void kernel_launch(void* const* d_in, const int* in_sizes, int n_in,
                              void* d_out, int out_size, void* d_ws, size_t ws_size,
                              hipStream_t stream) {
    const float* xj   = (const float*)d_in[0];
    const float* W0   = (const float*)d_in[1];
    const float* Ws   = (const float*)d_in[2];
    const float* Wout = (const float*)d_in[3];
    float* out = (float*)d_out;

    int n = in_sizes[0] / (D + 1);   // 4194304
    int nquads = n / 4;              // n is divisible by 4

    dim3 block(256);
    dim3 grid((nquads + block.x - 1) / block.x);
    nnflow_kernel<<<grid, block, 0, stream>>>(
        (const float4*)xj, W0, Ws, Wout, (float4*)out, nquads);
}

// Round 2
// 68.751 us; speedup vs baseline: 1.3449x; 1.3449x over previous
//
#include <hip/hip_runtime.h>

#define ALPHA 0.3f
#define D 2
#define DH 5
#define NH 3

// act(z) = 0.3 z + 0.7 tanh(z);  act'(z) = 0.3 + 0.7 (1 - tanh^2) = 1 - 0.7 t^2
// tanh(z) = 1 - 2/(e^{2z}+1), e^{2z} = 2^{z * 2*log2(e)}
__device__ __forceinline__ void act_pair(float z, float& h, float& d) {
    float e = __builtin_amdgcn_exp2f(z * 2.8853900817779268f); // v_mul + v_exp_f32
    float r = __builtin_amdgcn_rcpf(e + 1.0f);                 // v_add + v_rcp_f32
    float t = fmaf(-2.0f, r, 1.0f);                            // tanh(z)
    h = fmaf(0.3f, z, 0.7f * t);
    d = fmaf(-0.7f, t * t, 1.0f);
}

__global__ __launch_bounds__(256) void nnflow_kernel(
    const float4* __restrict__ xj4,
    const float* __restrict__ gW0,
    const float* __restrict__ gWs,
    const float* __restrict__ gWout,
    float4* __restrict__ out4,
    int nquads)
{
    int t = blockIdx.x * blockDim.x + threadIdx.x;
    if (t >= nquads) return;

    // ---- weights: uniform, compile-time indices -> SGPRs via s_load ----
    float w0[DH][D];
    #pragma unroll
    for (int k = 0; k < DH; ++k)
        #pragma unroll
        for (int j = 0; j < D; ++j)
            w0[k][j] = gW0[k * D + j];

    float ws[NH][DH][DH];
    #pragma unroll
    for (int i = 0; i < NH; ++i)
        #pragma unroll
        for (int k = 0; k < DH; ++k)
            #pragma unroll
            for (int j = 0; j < DH; ++j)
                ws[i][k][j] = gWs[(i * DH + k) * DH + j];

    float wo[D][DH];
    #pragma unroll
    for (int r = 0; r < D; ++r)
        #pragma unroll
        for (int j = 0; j < DH; ++j)
            wo[r][j] = gWout[r * DH + j];

    // ---- 4 samples = 12 floats = 3 float4, perfectly coalesced ----
    float4 v0 = xj4[(size_t)t * 3 + 0];
    float4 v1 = xj4[(size_t)t * 3 + 1];
    float4 v2 = xj4[(size_t)t * 3 + 2];

    float xs[4][3] = {
        {v0.x, v0.y, v0.z},
        {v0.w, v1.x, v1.y},
        {v1.z, v1.w, v2.x},
        {v2.y, v2.z, v2.w}
    };
    float os[4][3];

    #pragma unroll
    for (int s = 0; s < 4; ++s) {
        float x0 = xs[s][0], x1 = xs[s][1], lj = xs[s][2];

        // layer 0
        float h[DH], J0[DH], J1[DH];
        #pragma unroll
        for (int k = 0; k < DH; ++k) {
            float z = fmaf(w0[k][0], x0, w0[k][1] * x1);
            float hk, dk;
            act_pair(z, hk, dk);
            h[k]  = hk;
            J0[k] = dk * w0[k][0];
            J1[k] = dk * w0[k][1];
        }

        // hidden layers
        #pragma unroll
        for (int i = 0; i < NH; ++i) {
            float hn[DH], Jn0[DH], Jn1[DH];
            #pragma unroll
            for (int k = 0; k < DH; ++k) {
                float z = 0.f, j0 = 0.f, j1 = 0.f;
                #pragma unroll
                for (int j = 0; j < DH; ++j) {
                    float w = ws[i][k][j];
                    z  = fmaf(w, h[j],  z);
                    j0 = fmaf(w, J0[j], j0);
                    j1 = fmaf(w, J1[j], j1);
                }
                float hk, dk;
                act_pair(z, hk, dk);
                hn[k]  = hk;
                Jn0[k] = dk * j0;
                Jn1[k] = dk * j1;
            }
            #pragma unroll
            for (int k = 0; k < DH; ++k) { h[k] = hn[k]; J0[k] = Jn0[k]; J1[k] = Jn1[k]; }
        }

        // output layer (2x2 Jacobian)
        float y[2], Jo[2][2];
        #pragma unroll
        for (int r = 0; r < 2; ++r) {
            float z = 0.f, j0 = 0.f, j1 = 0.f;
            #pragma unroll
            for (int j = 0; j < DH; ++j) {
                float w = wo[r][j];
                z  = fmaf(w, h[j],  z);
                j0 = fmaf(w, J0[j], j0);
                j1 = fmaf(w, J1[j], j1);
            }
            float yk, dk;
            act_pair(z, yk, dk);
            y[r] = yk;
            Jo[r][0] = dk * j0;
            Jo[r][1] = dk * j1;
        }

        float det = fabsf(Jo[0][0] * Jo[1][1] - Jo[0][1] * Jo[1][0]);
        float ld = __builtin_amdgcn_logf(det) * 0.6931471805599453f; // ln = log2 * ln2

        os[s][0] = y[0];
        os[s][1] = y[1];
        os[s][2] = lj + ld;
    }

    out4[(size_t)t * 3 + 0] = make_float4(os[0][0], os[0][1], os[0][2], os[1][0]);
    out4[(size_t)t * 3 + 1] = make_float4(os[1][1], os[1][2], os[2][0], os[2][1]);
    out4[(size_t)t * 3 + 2] = make_float4(os[2][2], os[3][0], os[3][1], os[3][2]);
}

extern "C" void kernel_launch(void* const* d_in, const int* in_sizes, int n_in,
                              void* d_out, int out_size, void* d_ws, size_t ws_size,
                              hipStream_t stream) {
    const float* xj   = (const float*)d_in[0];
    const float* W0   = (const float*)d_in[1];
    const float* Ws   = (const float*)d_in[2];
    const float* Wout = (const float*)d_in[3];
    float* out = (float*)d_out;

    int n = in_sizes[0] / (D + 1);   // 4194304
    int nquads = n / 4;

    dim3 block(256);
    dim3 grid((nquads + block.x - 1) / block.x);
    nnflow_kernel<<<grid, block, 0, stream>>>(
        (const float4*)xj, W0, Ws, Wout, (float4*)out, nquads);
}